// Round 4
// baseline (102.365 us; speedup 1.0000x reference)
//
#include <hip/hip_runtime.h>

// PlaceCellNetwork forward: out = softmax(tanh([x,1] @ Wh^T + bh + prev @ Wf) @ Wo^T + bo)
// B=4M, IN=2, HID=20, OUT=10.
//
// R4: rounds 2/3 both ran ~100us with VGPR_Count=28 -- too few registers for
// the ~50 live floats, yet zero scratch traffic. Diagnosis: the compiler
// REMATERIALIZES prev[] / accumulators (re-loads from L1 per use inside the
// fully-unrolled loop) instead of keeping them live. Fix: pin every loaded
// value and accumulator with asm volatile("" : "+v"(v)) -- value becomes
// opaque, so later uses MUST read the register; remat is illegal.
// Also: bare v_exp_f32 via __builtin_amdgcn_exp2f (no OCML wrapper), and
// softmax max-pass removed (logits bounded by log2e*(|bo|+sum|Wo|) << 127,
// so exp2 cannot overflow; result mathematically identical).
//
// Algebra folded at repack (verified R3, absmax 2e-3):
//   a'' = 2*log2e*(Wh x + bh + Wf^T prev);  r = rcp(1+2^a'')
//   l'  = log2e*(bo+rowsum(Wo)) - 2*log2e*Wo . r ;  out = 2^l' / sum(2^l')

#define HID 20
#define OUT 10

typedef float f32x2 __attribute__((ext_vector_type(2)));

__device__ __forceinline__ float fast_rcp(float x) { return __builtin_amdgcn_rcpf(x); }
__device__ __forceinline__ float fast_exp2(float x) { return __builtin_amdgcn_exp2f(x); }

#define EACH10(F) F(0) F(1) F(2) F(3) F(4) F(5) F(6) F(7) F(8) F(9)
#define PIN(v) asm volatile("" : "+v"(v))

// ---- weight repack ----
// per-i block of 48 floats at ws[48*i]:
//   [0:1]=(S*Wh[i][0])x2  [2:3]=(S*Wh[i][1])x2  [4:5]=(S*(Wh[i][2]+bh[i]))x2
//   [6:7]=pad  [8+2o]=(S*Wf[o][i])x2  [28+2o]=(-S*Wo[o][i])x2
// ws[960+2o] = (L*(bo[o]+sum_i Wo[o][i]))x2 ; S=2*log2e, L=log2e
__global__ void repack_kernel(const float* __restrict__ Wh, const float* __restrict__ bh,
                              const float* __restrict__ Wo, const float* __restrict__ bo,
                              const float* __restrict__ Wf, float* __restrict__ ws) {
    const float S = 2.8853900817779268f;  // 2*log2(e)
    const float L = 1.4426950408889634f;  // log2(e)
    int t = threadIdx.x;
    if (t < HID) {
        float* b = ws + 48 * t;
        float w0 = S * Wh[3 * t + 0];
        float w1 = S * Wh[3 * t + 1];
        float wb = S * (Wh[3 * t + 2] + bh[t]);
        b[0] = w0; b[1] = w0;
        b[2] = w1; b[3] = w1;
        b[4] = wb; b[5] = wb;
        b[6] = 0.0f; b[7] = 0.0f;
        for (int o = 0; o < OUT; ++o) {
            float wf = S * Wf[o * HID + t];
            b[8 + 2 * o] = wf; b[9 + 2 * o] = wf;
            float wo = -S * Wo[o * HID + t];
            b[28 + 2 * o] = wo; b[29 + 2 * o] = wo;
        }
    } else if (t < HID + OUT) {
        int o = t - HID;
        float s = bo[o];
        for (int i = 0; i < HID; ++i) s += Wo[o * HID + i];
        float v = L * s;
        ws[960 + 2 * o] = v; ws[961 + 2 * o] = v;
    }
}

// ---- main kernel: 2 rows/thread (rowA,rowB) packed f32x2 ----
__global__ __launch_bounds__(256, 4) void pcn_kernel(
    const float* __restrict__ x, const float* __restrict__ prev,
    const float* __restrict__ w, float* __restrict__ out, int B) {
    const long t = (long)blockIdx.x * blockDim.x + threadIdx.x;
    const long r0 = 2 * t;
    if (r0 >= B) return;

#define LD2(p) (*reinterpret_cast<const f32x2*>(p))

    const float4 xv = *reinterpret_cast<const float4*>(x + 2 * r0);  // xA0,xA1,xB0,xB1
    const float4* pp = reinterpret_cast<const float4*>(prev + 10 * r0);
    const float4 q0 = pp[0], q1 = pp[1], q2 = pp[2], q3 = pp[3], q4 = pp[4];

    f32x2 x0 = {xv.x, xv.z};
    f32x2 x1 = {xv.y, xv.w};
    f32x2 p0 = {q0.x, q2.z}, p1 = {q0.y, q2.w}, p2 = {q0.z, q3.x},
          p3 = {q0.w, q3.y}, p4 = {q1.x, q3.z}, p5 = {q1.y, q3.w},
          p6 = {q1.z, q4.x}, p7 = {q1.w, q4.y}, p8 = {q2.x, q4.z},
          p9 = {q2.y, q4.w};

    // Pin: values become opaque -> compiler cannot re-load them from memory.
    PIN(x0); PIN(x1);
    PIN(p0); PIN(p1); PIN(p2); PIN(p3); PIN(p4);
    PIN(p5); PIN(p6); PIN(p7); PIN(p8); PIN(p9);

    // logit accumulators (exp2-domain), init = L*(bo + rowsum(Wo)); pinned.
#define INITL(o) f32x2 l##o = LD2(w + 960 + 2 * o); PIN(l##o);
    EACH10(INITL)
#undef INITL

    // stream hidden units; r_i = rcp(1+2^a) consumed immediately
#pragma unroll
    for (int i = 0; i < HID; ++i) {
        const float* wb = w + 48 * i;
        f32x2 a = LD2(wb + 4);
        a += LD2(wb + 0) * x0;
        a += LD2(wb + 2) * x1;
#define FB(o) a += LD2(wb + 8 + 2 * o) * p##o;
        EACH10(FB)
#undef FB
        f32x2 r;
        r.x = fast_rcp(1.0f + fast_exp2(a.x));
        r.y = fast_rcp(1.0f + fast_exp2(a.y));
#define LO(o) l##o += LD2(wb + 28 + 2 * o) * r;
        EACH10(LO)
#undef LO
    }

    // softmax in exp2 domain; logits bounded (|l| <~ 12) -> no max pass needed
#define EX(o) l##o.x = fast_exp2(l##o.x); l##o.y = fast_exp2(l##o.y);
    EACH10(EX)
#undef EX
    const f32x2 s = ((l0 + l1) + (l2 + l3)) + (((l4 + l5) + (l6 + l7)) + (l8 + l9));
    f32x2 rs;
    rs.x = fast_rcp(s.x);
    rs.y = fast_rcp(s.y);
#define SC(o) l##o *= rs;
    EACH10(SC)
#undef SC

    float4* op = reinterpret_cast<float4*>(out + 10 * r0);
    op[0] = make_float4(l0.x, l1.x, l2.x, l3.x);
    op[1] = make_float4(l4.x, l5.x, l6.x, l7.x);
    op[2] = make_float4(l8.x, l9.x, l0.y, l1.y);
    op[3] = make_float4(l2.y, l3.y, l4.y, l5.y);
    op[4] = make_float4(l6.y, l7.y, l8.y, l9.y);
#undef LD2
}

// ---- fallback (no workspace): 1 row/thread ----
__global__ __launch_bounds__(256) void pcn_fallback(
    const float* __restrict__ x, const float* __restrict__ prev,
    const float* __restrict__ Wh, const float* __restrict__ bh,
    const float* __restrict__ Wo, const float* __restrict__ bo,
    const float* __restrict__ Wf, float* __restrict__ out, int B) {
    const long r = (long)blockIdx.x * blockDim.x + threadIdx.x;
    if (r >= B) return;
    const float x0 = x[2 * r], x1 = x[2 * r + 1];
#define DECLP(o) float p##o = prev[10 * r + o]; PIN(p##o);
    EACH10(DECLP)
#undef DECLP
#define DECLL(o) float l##o = bo[o]; PIN(l##o);
    EACH10(DECLL)
#pragma unroll
    for (int i = 0; i < HID; ++i) {
        float a = fmaf(Wh[3 * i], x0, fmaf(Wh[3 * i + 1], x1, Wh[3 * i + 2] + bh[i]));
#define FB(o) a = fmaf(Wf[o * HID + i], p##o, a);
        EACH10(FB)
#undef FB
        const float h = 1.0f - 2.0f * fast_rcp(1.0f + __expf(2.0f * a));
#define LO(o) l##o = fmaf(Wo[o * HID + i], h, l##o);
        EACH10(LO)
#undef LO
    }
    float m = l0;
#define MX(o) m = fmaxf(m, l##o);
    MX(1) MX(2) MX(3) MX(4) MX(5) MX(6) MX(7) MX(8) MX(9)
#undef MX
    float s = 0.0f;
#define EX(o) l##o = __expf(l##o - m); s += l##o;
    EACH10(EX)
#undef EX
    const float rs = fast_rcp(s);
#define ST(o) out[10 * r + o] = l##o * rs;
    EACH10(ST)
#undef ST
}

extern "C" void kernel_launch(void* const* d_in, const int* in_sizes, int n_in,
                              void* d_out, int out_size, void* d_ws, size_t ws_size,
                              hipStream_t stream) {
    const float* x    = (const float*)d_in[0];
    const float* prev = (const float*)d_in[1];
    const float* Wh   = (const float*)d_in[2];
    const float* bh   = (const float*)d_in[3];
    const float* Wo   = (const float*)d_in[4];
    const float* bo   = (const float*)d_in[5];
    const float* Wf   = (const float*)d_in[6];
    float* out = (float*)d_out;

    const int B = in_sizes[0] / 2;

    if (ws_size >= 980 * sizeof(float)) {
        float* ws = (float*)d_ws;
        repack_kernel<<<1, 64, 0, stream>>>(Wh, bh, Wo, bo, Wf, ws);
        const int block = 256;
        const int grid = (B / 2 + block - 1) / block;  // 2 rows/thread
        pcn_kernel<<<grid, block, 0, stream>>>(x, prev, ws, out, B);
    } else {
        const int block = 256;
        const int grid = (B + block - 1) / block;
        pcn_fallback<<<grid, block, 0, stream>>>(x, prev, Wh, bh, Wo, bo, Wf, out, B);
    }
}

// Round 5
// 94.800 us; speedup vs baseline: 1.0798x; 1.0798x over previous
//
#include <hip/hip_runtime.h>

// PlaceCellNetwork forward: out = softmax(tanh([x,1] @ Wh^T + bh + prev @ Wf) @ Wo^T + bo)
// B=4M, IN=2, HID=20, OUT=10.
//
// R5: R2/R3/R4 all pinned at ~100-112us regardless of compute rewrites
// (VALUBusy 60->35% with constant duration, HBM 28%). Shared factor: AoS
// access -- each thread loads/stores a whole 40B row, so every prev-load and
// out-store is a wave64 dwordx4 with 80B lane stride = 64 scattered cache
// lines per instruction (~5-8x transaction inflation). Fix: LDS-staged
// transpose. All global traffic is now lane-dense float4; LDS redistributes.
//   phase1: dense stage prev -> LDS (row stride 11 words; odd = conflict-free)
//   phase2: per-thread row reads via ds_read_b32 offset-immediates
//   phase3: packed-f32x2 compute (identical math to R4, verified absmax 2e-3)
//   phase4: results -> LDS dense; phase5: dense float4 copy-out.
//
// Algebra folded at repack:
//   a'' = 2*log2e*(Wh x + bh + Wf^T prev);  r = rcp(1+2^a'')
//   l'  = log2e*(bo+rowsum(Wo)) - 2*log2e*Wo . r ;  out = 2^l' / sum(2^l')
// (logits bounded |l'| < ~12 -> no softmax max-pass needed in exp2 domain)

#define HID 20
#define OUT 10
#define RPB 512   // rows per block (256 threads x 2 rows)
#define PSTR 11   // LDS row stride in words for prev (odd -> conflict-free)

typedef float f32x2 __attribute__((ext_vector_type(2)));

__device__ __forceinline__ float fast_rcp(float x) { return __builtin_amdgcn_rcpf(x); }
__device__ __forceinline__ float fast_exp2(float x) { return __builtin_amdgcn_exp2f(x); }

#define EACH10(F) F(0) F(1) F(2) F(3) F(4) F(5) F(6) F(7) F(8) F(9)
#define PIN(v) asm volatile("" : "+v"(v))

// ---- weight repack (unchanged from R4; verified) ----
// per-i block of 48 floats at ws[48*i]:
//   [0:1]=(S*Wh[i][0])x2  [2:3]=(S*Wh[i][1])x2  [4:5]=(S*(Wh[i][2]+bh[i]))x2
//   [6:7]=pad  [8+2o]=(S*Wf[o][i])x2  [28+2o]=(-S*Wo[o][i])x2
// ws[960+2o] = (L*(bo[o]+sum_i Wo[o][i]))x2 ; S=2*log2e, L=log2e
__global__ void repack_kernel(const float* __restrict__ Wh, const float* __restrict__ bh,
                              const float* __restrict__ Wo, const float* __restrict__ bo,
                              const float* __restrict__ Wf, float* __restrict__ ws) {
    const float S = 2.8853900817779268f;  // 2*log2(e)
    const float L = 1.4426950408889634f;  // log2(e)
    int t = threadIdx.x;
    if (t < HID) {
        float* b = ws + 48 * t;
        float w0 = S * Wh[3 * t + 0];
        float w1 = S * Wh[3 * t + 1];
        float wb = S * (Wh[3 * t + 2] + bh[t]);
        b[0] = w0; b[1] = w0;
        b[2] = w1; b[3] = w1;
        b[4] = wb; b[5] = wb;
        b[6] = 0.0f; b[7] = 0.0f;
        for (int o = 0; o < OUT; ++o) {
            float wf = S * Wf[o * HID + t];
            b[8 + 2 * o] = wf; b[9 + 2 * o] = wf;
            float wo = -S * Wo[o * HID + t];
            b[28 + 2 * o] = wo; b[29 + 2 * o] = wo;
        }
    } else if (t < HID + OUT) {
        int o = t - HID;
        float s = bo[o];
        for (int i = 0; i < HID; ++i) s += Wo[o * HID + i];
        float v = L * s;
        ws[960 + 2 * o] = v; ws[961 + 2 * o] = v;
    }
}

// ---- main kernel ----
__global__ __launch_bounds__(256, 4) void pcn_kernel(
    const float* __restrict__ x, const float* __restrict__ prev,
    const float* __restrict__ w, float* __restrict__ out, int B) {
    __shared__ float lds[RPB * PSTR];   // 22528 B; reused for out-stage
    const int t = threadIdx.x;
    const long base = (long)blockIdx.x * RPB;
    const int V = (B - base < RPB) ? (int)(B - base) : RPB;  // valid rows
    const int NF = OUT * V;      // valid floats in this block's prev/out tile
    const int NF4 = NF >> 2;     // full float4s

    // ---- phase 1: dense global -> LDS stage of prev ----
    {
        const float4* src = reinterpret_cast<const float4*>(prev + base * OUT);
#pragma unroll
        for (int k = 0; k < 5; ++k) {
            const int idx = t + 256 * k;
            if (idx < NF4) {
                const float4 v = src[idx];
                const float vv[4] = {v.x, v.y, v.z, v.w};
                const int f0 = 4 * idx;
#pragma unroll
                for (int j = 0; j < 4; ++j) {
                    const int f = f0 + j;
                    const int r = f / OUT;           // magic-mul
                    lds[PSTR * r + (f - OUT * r)] = vv[j];
                }
            }
        }
        for (int f = (NF4 << 2) + t; f < NF; f += 256) {   // tail (rare)
            const int r = f / OUT;
            lds[PSTR * r + (f - OUT * r)] = prev[base * OUT + f];
        }
    }
    __syncthreads();

    // ---- phase 2: per-thread row gather from LDS + dense x loads ----
    const bool aok = t < V;            // rowA = base + t
    const bool bok = (t + 256) < V;    // rowB = base + t + 256
    const float* ra = lds + PSTR * t;
    const float* rb = lds + PSTR * (t + 256);

    f32x2 x0, x1;
    {
        f32x2 xa = {0.0f, 0.0f}, xb = {0.0f, 0.0f};
        if (aok) xa = *reinterpret_cast<const f32x2*>(x + 2 * (base + t));
        if (bok) xb = *reinterpret_cast<const f32x2*>(x + 2 * (base + t + 256));
        x0.x = xa.x; x0.y = xb.x;
        x1.x = xa.y; x1.y = xb.y;
    }
#define DECLP(o) f32x2 p##o; p##o.x = ra[o]; p##o.y = rb[o]; PIN(p##o);
    EACH10(DECLP)
#undef DECLP
    PIN(x0); PIN(x1);

    // ---- phase 3: packed compute (identical to R4 core) ----
#define LD2(p) (*reinterpret_cast<const f32x2*>(p))
#define INITL(o) f32x2 l##o = LD2(w + 960 + 2 * o);
    EACH10(INITL)
#undef INITL

#pragma unroll
    for (int i = 0; i < HID; ++i) {
        const float* wb = w + 48 * i;
        f32x2 a = LD2(wb + 4);
        a += LD2(wb + 0) * x0;
        a += LD2(wb + 2) * x1;
#define FB(o) a += LD2(wb + 8 + 2 * o) * p##o;
        EACH10(FB)
#undef FB
        f32x2 r;
        r.x = fast_rcp(1.0f + fast_exp2(a.x));
        r.y = fast_rcp(1.0f + fast_exp2(a.y));
#define LO(o) l##o += LD2(wb + 28 + 2 * o) * r;
        EACH10(LO)
#undef LO
    }

#define EX(o) l##o.x = fast_exp2(l##o.x); l##o.y = fast_exp2(l##o.y);
    EACH10(EX)
#undef EX
    const f32x2 s = ((l0 + l1) + (l2 + l3)) + (((l4 + l5) + (l6 + l7)) + (l8 + l9));
    f32x2 rs;
    rs.x = fast_rcp(s.x);
    rs.y = fast_rcp(s.y);
#define SC(o) l##o *= rs;
    EACH10(SC)
#undef SC
#undef LD2

    // ---- phase 4: results -> LDS (dense, stride 10 words; 8B-aligned b64s) ----
    __syncthreads();   // all LDS row-reads done before overwrite
    if (aok) {
        f32x2* d = reinterpret_cast<f32x2*>(lds + 10 * t);
        d[0].x = l0.x; d[0].y = l1.x;
        d[1].x = l2.x; d[1].y = l3.x;
        d[2].x = l4.x; d[2].y = l5.x;
        d[3].x = l6.x; d[3].y = l7.x;
        d[4].x = l8.x; d[4].y = l9.x;
    }
    if (bok) {
        f32x2* d = reinterpret_cast<f32x2*>(lds + 10 * (t + 256));
        d[0].x = l0.y; d[0].y = l1.y;
        d[1].x = l2.y; d[1].y = l3.y;
        d[2].x = l4.y; d[2].y = l5.y;
        d[3].x = l6.y; d[3].y = l7.y;
        d[4].x = l8.y; d[4].y = l9.y;
    }
    __syncthreads();

    // ---- phase 5: dense LDS -> global copy-out ----
    {
        float4* dst = reinterpret_cast<float4*>(out + base * OUT);
        const float4* sl = reinterpret_cast<const float4*>(lds);
#pragma unroll
        for (int k = 0; k < 5; ++k) {
            const int idx = t + 256 * k;
            if (idx < NF4) dst[idx] = sl[idx];
        }
        for (int f = (NF4 << 2) + t; f < NF; f += 256) {
            out[base * OUT + f] = lds[f];
        }
    }
}

// ---- fallback (no workspace): 1 row/thread ----
__global__ __launch_bounds__(256) void pcn_fallback(
    const float* __restrict__ x, const float* __restrict__ prev,
    const float* __restrict__ Wh, const float* __restrict__ bh,
    const float* __restrict__ Wo, const float* __restrict__ bo,
    const float* __restrict__ Wf, float* __restrict__ out, int B) {
    const long r = (long)blockIdx.x * blockDim.x + threadIdx.x;
    if (r >= B) return;
    const float x0 = x[2 * r], x1 = x[2 * r + 1];
#define DECLP(o) float p##o = prev[10 * r + o];
    EACH10(DECLP)
#undef DECLP
#define DECLL(o) float l##o = bo[o];
    EACH10(DECLL)
#undef DECLL
#pragma unroll
    for (int i = 0; i < HID; ++i) {
        float a = fmaf(Wh[3 * i], x0, fmaf(Wh[3 * i + 1], x1, Wh[3 * i + 2] + bh[i]));
#define FB(o) a = fmaf(Wf[o * HID + i], p##o, a);
        EACH10(FB)
#undef FB
        const float h = 1.0f - 2.0f * fast_rcp(1.0f + __expf(2.0f * a));
#define LO(o) l##o = fmaf(Wo[o * HID + i], h, l##o);
        EACH10(LO)
#undef LO
    }
    float m = l0;
#define MX(o) m = fmaxf(m, l##o);
    MX(1) MX(2) MX(3) MX(4) MX(5) MX(6) MX(7) MX(8) MX(9)
#undef MX
    float s = 0.0f;
#define EX(o) l##o = __expf(l##o - m); s += l##o;
    EACH10(EX)
#undef EX
    const float rs = fast_rcp(s);
#define ST(o) out[10 * r + o] = l##o * rs;
    EACH10(ST)
#undef ST
}

extern "C" void kernel_launch(void* const* d_in, const int* in_sizes, int n_in,
                              void* d_out, int out_size, void* d_ws, size_t ws_size,
                              hipStream_t stream) {
    const float* x    = (const float*)d_in[0];
    const float* prev = (const float*)d_in[1];
    const float* Wh   = (const float*)d_in[2];
    const float* bh   = (const float*)d_in[3];
    const float* Wo   = (const float*)d_in[4];
    const float* bo   = (const float*)d_in[5];
    const float* Wf   = (const float*)d_in[6];
    float* out = (float*)d_out;

    const int B = in_sizes[0] / 2;

    if (ws_size >= 980 * sizeof(float)) {
        float* ws = (float*)d_ws;
        repack_kernel<<<1, 64, 0, stream>>>(Wh, bh, Wo, bo, Wf, ws);
        const int grid = (B + RPB - 1) / RPB;
        pcn_kernel<<<grid, 256, 0, stream>>>(x, prev, ws, out, B);
    } else {
        const int block = 256;
        const int grid = (B + block - 1) / block;
        pcn_fallback<<<grid, block, 0, stream>>>(x, prev, Wh, bh, Wo, bo, Wf, out, B);
    }
}